// Round 4
// baseline (132.779 us; speedup 1.0000x reference)
//
#include <hip/hip_runtime.h>
#include <math.h>

#define N_ENTC 30000
#define ALL_RELC 221
#define NDIM 32
#define EVAL_RELC 86
#define BB 16
#define NE 120000
#define ROW 512            /* BB*NDIM floats per qacc row */
#define NSCAN 120          /* scan stripes; NSCAN*EPB == NE */
#define EPB 1000
#define MW 938             /* bitmask words for 30000 entities */
#define MAXL 256           /* compacted-list capacity per (layer,direction) */

// Two regular (graph-capturable) dispatches; hidB/hidC eliminated (~8 MB ws).
//  K1 k_scan   : 120 blocks [round-3 proven, unchanged]. Per-stripe records,
//                counts, block0: relw -> global, block1: zero qacc + done.
//  K2 k_gather : 120 blocks. ONCE per block (all waves parallel): preload
//                rel0/relw/src-emb/Wlin0 to LDS and compact ALL stripes'
//                records into LDS lists (4 threads per stripe -> every global
//                load issued concurrently; no serial stripe walk). Then
//                grid-stride over L2 records: match against LDS L1 list,
//                pre[b][k] -> lin1 -> msg2 atomic (pure LDS inner loops).
//                Fin on last block via threadfence+done counter [r3 proven].

__global__ __launch_bounds__(512) void k_scan(
    const int* __restrict__ head, const int* __restrict__ tail,
    const int* __restrict__ eh, const int* __restrict__ et,
    const int* __restrict__ er, const float* __restrict__ ew,
    const float* __restrict__ ent_emb,
    const float* __restrict__ Wrel, const float* __restrict__ brel,
    const float* __restrict__ Watt, const float* __restrict__ batt,
    int4* __restrict__ recs, int* __restrict__ counts,
    float* __restrict__ relwG, float* __restrict__ qaccB,
    int* __restrict__ done)
{
    __shared__ unsigned mH[MW], mT[MW];
    __shared__ int s_src[32];
    __shared__ int s_cnt[4];
    __shared__ float s_ht[BB * 64];
    __shared__ float s_h5[BB * 5];
    const int t = threadIdx.x, bid = blockIdx.x;

    if (t < 32) s_src[t] = (t < BB) ? head[t] : tail[t - BB];
    for (int i = t; i < MW; i += 512) { mH[i] = 0u; mT[i] = 0u; }
    if (t < 4) s_cnt[t] = 0;
    __syncthreads();
    if (t < BB) {
        int h = s_src[t], q = s_src[BB + t];
        atomicOr(&mH[h >> 5], 1u << (h & 31));
        atomicOr(&mT[q >> 5], 1u << (q & 31));
    }
    __syncthreads();

    const int e0 = bid * EPB;
    const int4* eh4 = (const int4*)(eh + e0);
    const int4* et4 = (const int4*)(et + e0);
    for (int p = t; p < EPB / 4; p += 512) {
        int4 h4 = eh4[p], t4 = et4[p];
        int hv[4] = {h4.x, h4.y, h4.z, h4.w};
        int tv[4] = {t4.x, t4.y, t4.z, t4.w};
#pragma unroll
        for (int c = 0; c < 4; c++) {
            int e = e0 + 4 * p + c, h = hv[c], tt = tv[c];
            bool hH = (mH[h >> 5] >> (h & 31)) & 1u;
            bool hT = (mT[h >> 5] >> (h & 31)) & 1u;
            bool tT = (mT[tt >> 5] >> (tt & 31)) & 1u;
            bool tH = (mH[tt >> 5] >> (tt & 31)) & 1u;
            if (!(hH | hT | tT | tH)) continue;
            int r = er[e];
            int wb = __float_as_int(ew[e]);
            if (hH) { // d=0 layer-1: srcmask over head ids
                unsigned m = 0;
#pragma unroll
                for (int b = 0; b < BB; b++) m |= (s_src[b] == h) ? (1u << b) : 0u;
                int pos = atomicAdd(&s_cnt[0], 1);
                recs[(size_t)bid * EPB + pos] = make_int4(tt, r | (int)(m << 8), wb, h);
            }
            if (hT) { // d=1 layer-1: srcmask over tail ids
                unsigned m = 0;
#pragma unroll
                for (int b = 0; b < BB; b++) m |= (s_src[BB + b] == h) ? (1u << b) : 0u;
                int pos = atomicAdd(&s_cnt[1], 1);
                recs[(size_t)NE + bid * EPB + pos] = make_int4(tt, r | (int)(m << 8), wb, h);
            }
            if (tT) { // d=0 layer-2: canon = first matching tail slot
                unsigned m = 0;
#pragma unroll
                for (int b = 0; b < BB; b++) m |= (s_src[BB + b] == tt) ? (1u << b) : 0u;
                int canon = __ffs(m) - 1;
                int pos = atomicAdd(&s_cnt[2], 1);
                recs[(size_t)2 * NE + bid * EPB + pos] = make_int4(h, r | (canon << 8), wb, tt);
            }
            if (tH) { // d=1 layer-2: canon = first matching head slot
                unsigned m = 0;
#pragma unroll
                for (int b = 0; b < BB; b++) m |= (s_src[b] == tt) ? (1u << b) : 0u;
                int canon = __ffs(m) - 1;
                int pos = atomicAdd(&s_cnt[3], 1);
                recs[(size_t)3 * NE + bid * EPB + pos] = make_int4(h, r | (canon << 8), wb, tt);
            }
        }
    }
    __syncthreads();
    if (t < 4) counts[bid * 4 + t] = s_cnt[t];

    if (bid == 1) { // zero qacc (both directions) + done counter
        for (int i = t; i < 2 * BB * ROW; i += 512) qaccB[i] = 0.f;
        if (t == 0) *done = 0;
    }
    if (bid == 0) { // relation-attention weights -> global (proven math)
        for (int i = t; i < BB * NDIM; i += 512) {
            int b = i >> 5, k = i & 31;
            s_ht[b * 64 + k] = ent_emb[(size_t)s_src[b] * NDIM + k];
            s_ht[b * 64 + 32 + k] = ent_emb[(size_t)s_src[BB + b] * NDIM + k];
        }
        __syncthreads();
        for (int l = 0; l < 2; l++) {
            for (int i = t; i < BB * 5; i += 512) {
                int b = i / 5, j = i % 5;
                float s = brel[l * 5 + j];
                for (int k = 0; k < 64; k++)
                    s += s_ht[b * 64 + k] * Wrel[l * 320 + k * 5 + j];
                s_h5[i] = fmaxf(s, 0.f);
            }
            __syncthreads();
            for (int i = t; i < BB * ALL_RELC; i += 512) {
                int b = i / ALL_RELC, r = i % ALL_RELC;
                float s = batt[l * ALL_RELC + r];
                for (int j = 0; j < 5; j++)
                    s += s_h5[b * 5 + j] * Watt[l * 5 * ALL_RELC + j * ALL_RELC + r];
                relwG[l * BB * ALL_RELC + i] = 1.0f / (1.0f + expf(-s));
            }
            __syncthreads();
        }
    }
}

__global__ __launch_bounds__(512) void k_gather(
    const int* __restrict__ head, const int* __restrict__ tail,
    const float* __restrict__ ent_emb, const float* __restrict__ rel_embs,
    const float* __restrict__ Wlin, const float* __restrict__ blin,
    const float* __restrict__ Wr, const float* __restrict__ br,
    const int4* __restrict__ recs, const int* __restrict__ counts,
    const float* __restrict__ relwG, float* __restrict__ qaccB,
    int* __restrict__ done, float* __restrict__ out)
{
    __shared__ int s_src[32];
    __shared__ int s_cnt[NSCAN * 4];
    __shared__ float s_rel0[ALL_RELC * NDIM];      // 28 KB: layer-0 rel emb
    __shared__ float s_relw[2 * BB * ALL_RELC];    // 28 KB: [l][b][r]
    __shared__ float s_emb[32 * NDIM];             // 4 KB: src entity rows
    __shared__ int4 s_l1[2][MAXL];
    __shared__ int4 s_l2[2][MAXL];
    __shared__ int s_lc[4];                        // l1c0,l1c1,l2c0,l2c1
    __shared__ float sW[NDIM * NDIM];
    __shared__ float sb[NDIM];
    __shared__ float s_pre[BB][NDIM];
    __shared__ float sx[BB * 128];                 // fin: hemb|temb|hh|th
    __shared__ int s_canon[2][BB];
    __shared__ int s_last;
    const int t = threadIdx.x, bid = blockIdx.x;

    // ---- phase 0: parallel preloads ----
    if (t < 32) s_src[t] = (t < BB) ? head[t] : tail[t - BB];
    if (t < NSCAN) ((int4*)s_cnt)[t] = ((const int4*)counts)[t];
    for (int i = t; i < ALL_RELC * NDIM / 4; i += 512)
        ((float4*)s_rel0)[i] = ((const float4*)rel_embs)[i];
    for (int i = t; i < 2 * BB * ALL_RELC / 4; i += 512)
        ((float4*)s_relw)[i] = ((const float4*)relwG)[i];
    for (int i = t; i < NDIM * NDIM; i += 512) sW[i] = Wlin[i]; // layer 0
    if (t < NDIM) sb[t] = blin[t];
    if (t < 4) s_lc[t] = 0;
    __syncthreads();

    // ---- phase 1: src-emb preload + compact ALL records into LDS lists ----
    for (int i = t; i < 32 * NDIM; i += 512)
        s_emb[i] = ent_emb[(size_t)s_src[i >> 5] * NDIM + (i & 31)];
    {
        // 4 threads per stripe -> all stripes' loads issued concurrently
        const int ss = t >> 2, slot = t & 3;
        if (ss < NSCAN) {
#pragma unroll
            for (int li = 0; li < 4; li++) {
                int c = s_cnt[ss * 4 + li];
                int dd = li & 1;
                for (int q = slot; q < c; q += 4) {
                    int4 lr = recs[(size_t)li * NE + (size_t)ss * EPB + q];
                    int pos = atomicAdd(&s_lc[li], 1);
                    if (li < 2) { if (pos < MAXL) s_l1[dd][pos] = lr; }
                    else        { if (pos < MAXL) s_l2[dd][pos] = lr; }
                }
            }
        }
    }
    __syncthreads();

    // ---- phase 2: grid-strided L2 records (pure-LDS inner loops) ----
    const int c10 = min(s_lc[0], MAXL), c11 = min(s_lc[1], MAXL);
    const int tot0 = min(s_lc[2], MAXL), tot1 = min(s_lc[3], MAXL);
    const int tot = tot0 + tot1;
    const int b = t >> 5, k = t & 31;
    const float* rel1 = rel_embs + (size_t)ALL_RELC * NDIM;
    for (int g = bid; g < tot; g += NSCAN) {
        const int d = (g >= tot0) ? 1 : 0;
        int4 rec = s_l2[d][d ? g - tot0 : g];
        const int hrow = rec.x, r = rec.y & 255, canon = (rec.y >> 8) & 15;
        const float w = __int_as_float(rec.z);
        // pre[b][k]: gather matched layer-1 messages (== proven msg1 sums)
        {
            float ek = s_emb[(d * BB + b) * NDIM + k];
            float acc = 0.f;
            const int c1 = d ? c11 : c10;
            for (int m = 0; m < c1; m++) {
                int4 lr = s_l1[d][m];
                if (lr.x != hrow) continue;
                unsigned msk = ((unsigned)lr.y) >> 8;
                if (!((msk >> b) & 1u)) continue;
                int rr = lr.y & 255;
                acc += s_relw[b * ALL_RELC + rr] * __int_as_float(lr.z)
                     * ek * s_rel0[rr * NDIM + k];
            }
            s_pre[b][k] = acc;
        }
        __syncthreads();
        // lin1 (relu) + layer-2 message into qacc[canon]  (thread = (b, j=k))
        {
            float a = sb[k];
            for (int kk = 0; kk < NDIM; kk++)
                a += s_pre[b][kk] * sW[kk * NDIM + k];
            float cf = s_relw[BB * ALL_RELC + b * ALL_RELC + r] * w;
            float v = fmaxf(a, 0.f) * cf * rel1[r * NDIM + k];
            atomicAdd(qaccB + (size_t)d * BB * ROW + canon * ROW + b * NDIM + k, v);
        }
        __syncthreads(); // s_pre reused next record
    }

    // ---- last-block fin [round-3 proven] ----
    __threadfence(); // my qacc atomics visible before counter bump
    if (t == 0) {
        int old = atomicAdd(done, 1);
        s_last = (old == NSCAN - 1) ? 1 : 0;
    }
    __syncthreads();
    if (!s_last) return;
    __threadfence(); // acquire: all other blocks' qacc atomics

    for (int i = t; i < NDIM * NDIM; i += 512) sW[i] = Wlin[NDIM * NDIM + i]; // layer 1
    if (t < NDIM) sb[t] = blin[NDIM + t];
    if (t < 2 * BB) {
        int dd = t >> 4, bq = t & 15;
        int q = s_src[(1 - dd) * BB + bq];
        int c = 0;
        for (int bb = 0; bb < BB; bb++)
            if (s_src[(1 - dd) * BB + bb] == q) { c = bb; break; }
        s_canon[dd][bq] = c;
    }
    {
        int bq = t >> 5, kk = t & 31;
        sx[bq * 128 + kk] = ent_emb[(size_t)s_src[bq] * NDIM + kk];           // hemb
        sx[bq * 128 + 32 + kk] = ent_emb[(size_t)s_src[BB + bq] * NDIM + kk]; // temb
    }
    __syncthreads();
    for (int dd = 0; dd < 2; dd++) { // layer-2 linear on (canon,b) segments
        int bq = t >> 5, j = t & 31;
        const float* hrow = qaccB + (size_t)dd * BB * ROW + s_canon[dd][bq] * ROW + bq * NDIM;
        float s = sb[j];
        for (int kk = 0; kk < NDIM; kk++)
            s += hrow[kk] * sW[kk * NDIM + j];
        // d=0 (init=head, query=tail) -> tail_hid (col 96); d=1 -> head_hid (col 64)
        sx[bq * 128 + (dd == 0 ? 96 : 64) + j] = fmaxf(s, 0.f);
    }
    __syncthreads();
    for (int o = t; o < BB * EVAL_RELC; o += 512) {
        int bq = o / EVAL_RELC, r = o % EVAL_RELC;
        float s = br[r];
        for (int kk = 0; kk < 128; kk++)
            s += sx[bq * 128 + kk] * Wr[kk * EVAL_RELC + r];
        out[o] = s;
    }
}

extern "C" void kernel_launch(void* const* d_in, const int* in_sizes, int n_in,
                              void* d_out, int out_size, void* d_ws,
                              size_t ws_size, hipStream_t stream)
{
    const int* head = (const int*)d_in[0];
    const int* tail = (const int*)d_in[1];
    const int* eh = (const int*)d_in[2];
    const int* et = (const int*)d_in[3];
    const int* er = (const int*)d_in[4];
    const float* ew = (const float*)d_in[5];
    const float* ent_emb = (const float*)d_in[6];
    const float* rel_embs = (const float*)d_in[7];
    const float* Wlin = (const float*)d_in[8];
    const float* blin = (const float*)d_in[9];
    const float* Wrel = (const float*)d_in[10];
    const float* brel = (const float*)d_in[11];
    const float* Watt = (const float*)d_in[12];
    const float* batt = (const float*)d_in[13];
    const float* Wr = (const float*)d_in[14];
    const float* br = (const float*)d_in[15];
    float* out = (float*)d_out;
    float* ws = (float*)d_ws;

    // ---- workspace carve (~8 MB) ----
    int4* recs = (int4*)ws;                           // [4][NE] int4
    int* counts = (int*)(recs + (size_t)4 * NE);      // [NSCAN][4]
    float* relwG = (float*)(counts + 4 * NSCAN);      // 2*BB*ALL_RELC floats
    float* qaccB = relwG + 2 * BB * ALL_RELC;         // [2][16][512]
    int* done = (int*)(qaccB + (size_t)2 * BB * ROW); // 1 int

    k_scan<<<NSCAN, 512, 0, stream>>>(head, tail, eh, et, er, ew, ent_emb,
                                      Wrel, brel, Watt, batt,
                                      recs, counts, relwG, qaccB, done);
    k_gather<<<NSCAN, 512, 0, stream>>>(head, tail, ent_emb, rel_embs,
                                        Wlin, blin, Wr, br, recs, counts,
                                        relwG, qaccB, done, out);
}

// Round 5
// 130.921 us; speedup vs baseline: 1.0142x; 1.0142x over previous
//
#include <hip/hip_runtime.h>
#include <math.h>

#define N_ENTC 30000
#define ALL_RELC 221
#define NDIM 32
#define EVAL_RELC 86
#define BB 16
#define NE 120000
#define ROW 512            /* BB*NDIM floats per qacc row */
#define NSCAN 120          /* scan stripes; NSCAN*EPB == NE */
#define EPB 1000
#define MW 938             /* bitmask words for 30000 entities */
#define MAXL 256           /* compacted-list capacity per (layer,direction) */

// Two regular dispatches; no cross-kernel handoff of kernel-produced tables.
//  K1 k_scan   : 120 blocks. Per-stripe records + counts (proven format).
//                block1: zero qacc + done. (relw phase REMOVED -> shorter.)
//  K2 k_gather : 120 blocks. Slim startup, all parallel: counts + src-emb +
//                Wlin0 + compact ~500 recs into LDS lists; relation-attention
//                weights RECOMPUTED in-block from clean inputs (23K MAC --
//                cheaper than staging 28 KB of dirty kernel output per block).
//                Then grid-stride over L2 records: match vs LDS L1 list,
//                pre[b][k] -> lin1 -> msg2 atomic (proven r4 math).
//                Fin on last block via threadfence+done counter [r3 proven].

__global__ __launch_bounds__(512) void k_scan(
    const int* __restrict__ head, const int* __restrict__ tail,
    const int* __restrict__ eh, const int* __restrict__ et,
    const int* __restrict__ er, const float* __restrict__ ew,
    int4* __restrict__ recs, int* __restrict__ counts,
    float* __restrict__ qaccB, int* __restrict__ done)
{
    __shared__ unsigned mH[MW], mT[MW];
    __shared__ int s_src[32];
    __shared__ int s_cnt[4];
    const int t = threadIdx.x, bid = blockIdx.x;

    if (t < 32) s_src[t] = (t < BB) ? head[t] : tail[t - BB];
    for (int i = t; i < MW; i += 512) { mH[i] = 0u; mT[i] = 0u; }
    if (t < 4) s_cnt[t] = 0;
    __syncthreads();
    if (t < BB) {
        int h = s_src[t], q = s_src[BB + t];
        atomicOr(&mH[h >> 5], 1u << (h & 31));
        atomicOr(&mT[q >> 5], 1u << (q & 31));
    }
    __syncthreads();

    const int e0 = bid * EPB;
    const int4* eh4 = (const int4*)(eh + e0);
    const int4* et4 = (const int4*)(et + e0);
    for (int p = t; p < EPB / 4; p += 512) {
        int4 h4 = eh4[p], t4 = et4[p];
        int hv[4] = {h4.x, h4.y, h4.z, h4.w};
        int tv[4] = {t4.x, t4.y, t4.z, t4.w};
#pragma unroll
        for (int c = 0; c < 4; c++) {
            int e = e0 + 4 * p + c, h = hv[c], tt = tv[c];
            bool hH = (mH[h >> 5] >> (h & 31)) & 1u;
            bool hT = (mT[h >> 5] >> (h & 31)) & 1u;
            bool tT = (mT[tt >> 5] >> (tt & 31)) & 1u;
            bool tH = (mH[tt >> 5] >> (tt & 31)) & 1u;
            if (!(hH | hT | tT | tH)) continue;
            int r = er[e];
            int wb = __float_as_int(ew[e]);
            if (hH) { // d=0 layer-1: srcmask over head ids
                unsigned m = 0;
#pragma unroll
                for (int b = 0; b < BB; b++) m |= (s_src[b] == h) ? (1u << b) : 0u;
                int pos = atomicAdd(&s_cnt[0], 1);
                recs[(size_t)bid * EPB + pos] = make_int4(tt, r | (int)(m << 8), wb, h);
            }
            if (hT) { // d=1 layer-1: srcmask over tail ids
                unsigned m = 0;
#pragma unroll
                for (int b = 0; b < BB; b++) m |= (s_src[BB + b] == h) ? (1u << b) : 0u;
                int pos = atomicAdd(&s_cnt[1], 1);
                recs[(size_t)NE + bid * EPB + pos] = make_int4(tt, r | (int)(m << 8), wb, h);
            }
            if (tT) { // d=0 layer-2: canon = first matching tail slot
                unsigned m = 0;
#pragma unroll
                for (int b = 0; b < BB; b++) m |= (s_src[BB + b] == tt) ? (1u << b) : 0u;
                int canon = __ffs(m) - 1;
                int pos = atomicAdd(&s_cnt[2], 1);
                recs[(size_t)2 * NE + bid * EPB + pos] = make_int4(h, r | (canon << 8), wb, tt);
            }
            if (tH) { // d=1 layer-2: canon = first matching head slot
                unsigned m = 0;
#pragma unroll
                for (int b = 0; b < BB; b++) m |= (s_src[b] == tt) ? (1u << b) : 0u;
                int canon = __ffs(m) - 1;
                int pos = atomicAdd(&s_cnt[3], 1);
                recs[(size_t)3 * NE + bid * EPB + pos] = make_int4(h, r | (canon << 8), wb, tt);
            }
        }
    }
    __syncthreads();
    if (t < 4) counts[bid * 4 + t] = s_cnt[t];

    if (bid == 1) { // zero qacc (both directions) + done counter
        for (int i = t; i < 2 * BB * ROW; i += 512) qaccB[i] = 0.f;
        if (t == 0) *done = 0;
    }
}

__global__ __launch_bounds__(512) void k_gather(
    const int* __restrict__ head, const int* __restrict__ tail,
    const float* __restrict__ ent_emb, const float* __restrict__ rel_embs,
    const float* __restrict__ Wlin, const float* __restrict__ blin,
    const float* __restrict__ Wrel, const float* __restrict__ brel,
    const float* __restrict__ Watt, const float* __restrict__ batt,
    const float* __restrict__ Wr, const float* __restrict__ br,
    const int4* __restrict__ recs, const int* __restrict__ counts,
    float* __restrict__ qaccB, int* __restrict__ done,
    float* __restrict__ out)
{
    __shared__ int s_src[32];
    __shared__ int s_cnt[NSCAN * 4];
    __shared__ float s_ht[BB * 64];              // [b][head(32)|tail(32)]
    __shared__ float s_h5[2 * BB * 5];           // [l][b][j]
    __shared__ float s_relw[2 * BB * ALL_RELC];  // [l][b][r] (recomputed)
    __shared__ int4 s_l1[2][MAXL];
    __shared__ int4 s_l2[2][MAXL];
    __shared__ int s_lc[4];                      // l1c0,l1c1,l2c0,l2c1
    __shared__ float sW[NDIM * NDIM];
    __shared__ float sb[NDIM];
    __shared__ float s_pre[BB][NDIM];
    __shared__ float sx[BB * 128];               // fin: hemb|temb|hh|th
    __shared__ int s_canon[2][BB];
    __shared__ int s_last;
    const int t = threadIdx.x, bid = blockIdx.x;

    // ---- phase 0: parallel preloads (all clean inputs / tiny counts) ----
    if (t < 32) s_src[t] = (t < BB) ? head[t] : tail[t - BB];
    if (t < NSCAN) ((int4*)s_cnt)[t] = ((const int4*)counts)[t];
    for (int i = t; i < NDIM * NDIM; i += 512) sW[i] = Wlin[i]; // layer 0
    if (t < NDIM) sb[t] = blin[t];
    if (t < 4) s_lc[t] = 0;
    __syncthreads();

    // ---- phase 1a: src-emb (ht concat) preload ----
    for (int i = t; i < BB * NDIM; i += 512) {
        int b = i >> 5, k = i & 31;
        s_ht[b * 64 + k] = ent_emb[(size_t)s_src[b] * NDIM + k];
        s_ht[b * 64 + 32 + k] = ent_emb[(size_t)s_src[BB + b] * NDIM + k];
    }
    // ---- phase 1b: compact ALL stripes' records into LDS lists ----
    {
        // 4 threads per stripe -> all stripes' loads issued concurrently
        const int ss = t >> 2, slot = t & 3;
        if (ss < NSCAN) {
#pragma unroll
            for (int li = 0; li < 4; li++) {
                int c = s_cnt[ss * 4 + li];
                int dd = li & 1;
                for (int q = slot; q < c; q += 4) {
                    int4 lr = recs[(size_t)li * NE + (size_t)ss * EPB + q];
                    int pos = atomicAdd(&s_lc[li], 1);
                    if (li < 2) { if (pos < MAXL) s_l1[dd][pos] = lr; }
                    else        { if (pos < MAXL) s_l2[dd][pos] = lr; }
                }
            }
        }
    }
    __syncthreads();

    // ---- phase 2: recompute relation-attention weights (proven math) ----
    if (t < 2 * BB * 5) { // h5[l][b][j] = relu(ht @ Wrel[l] + brel[l])
        int l = t / (BB * 5), rem = t % (BB * 5), b = rem / 5, j = rem % 5;
        float s = brel[l * 5 + j];
        for (int k = 0; k < 64; k++)
            s += s_ht[b * 64 + k] * Wrel[l * 320 + k * 5 + j];
        s_h5[t] = fmaxf(s, 0.f);
    }
    __syncthreads();
    for (int i = t; i < 2 * BB * ALL_RELC; i += 512) {
        int l = i / (BB * ALL_RELC), rem = i % (BB * ALL_RELC);
        int b = rem / ALL_RELC, r = rem % ALL_RELC;
        float s = batt[l * ALL_RELC + r];
        for (int j = 0; j < 5; j++)
            s += s_h5[l * BB * 5 + b * 5 + j] * Watt[l * 5 * ALL_RELC + j * ALL_RELC + r];
        s_relw[i] = 1.0f / (1.0f + expf(-s));
    }
    __syncthreads();

    // ---- phase 3: grid-strided L2 records (LDS lists, proven r4 math) ----
    const int c10 = min(s_lc[0], MAXL), c11 = min(s_lc[1], MAXL);
    const int tot0 = min(s_lc[2], MAXL), tot1 = min(s_lc[3], MAXL);
    const int tot = tot0 + tot1;
    const int b = t >> 5, k = t & 31;
    const float* rel1 = rel_embs + (size_t)ALL_RELC * NDIM;
    for (int g = bid; g < tot; g += NSCAN) {
        const int d = (g >= tot0) ? 1 : 0;
        int4 rec = s_l2[d][d ? g - tot0 : g];
        const int hrow = rec.x, r = rec.y & 255, canon = (rec.y >> 8) & 15;
        const float w = __int_as_float(rec.z);
        // pre[b][k]: gather matched layer-1 messages (== proven msg1 sums)
        {
            float ek = s_ht[b * 64 + d * 32 + k];
            float acc = 0.f;
            const int c1 = d ? c11 : c10;
            for (int m = 0; m < c1; m++) {
                int4 lr = s_l1[d][m];
                if (lr.x != hrow) continue;
                unsigned msk = ((unsigned)lr.y) >> 8;
                if (!((msk >> b) & 1u)) continue;
                int rr = lr.y & 255;
                acc += s_relw[b * ALL_RELC + rr] * __int_as_float(lr.z)
                     * ek * rel_embs[rr * NDIM + k];
            }
            s_pre[b][k] = acc;
        }
        __syncthreads();
        // lin1 (relu) + layer-2 message into qacc[canon]  (thread = (b, j=k))
        {
            float a = sb[k];
            for (int kk = 0; kk < NDIM; kk++)
                a += s_pre[b][kk] * sW[kk * NDIM + k];
            float cf = s_relw[BB * ALL_RELC + b * ALL_RELC + r] * w;
            float v = fmaxf(a, 0.f) * cf * rel1[r * NDIM + k];
            atomicAdd(qaccB + (size_t)d * BB * ROW + canon * ROW + b * NDIM + k, v);
        }
        __syncthreads(); // s_pre reused next record
    }

    // ---- last-block fin [round-3/4 proven] ----
    __threadfence(); // my qacc atomics visible before counter bump
    if (t == 0) {
        int old = atomicAdd(done, 1);
        s_last = (old == NSCAN - 1) ? 1 : 0;
    }
    __syncthreads();
    if (!s_last) return;
    __threadfence(); // acquire: all other blocks' qacc atomics

    for (int i = t; i < NDIM * NDIM; i += 512) sW[i] = Wlin[NDIM * NDIM + i]; // layer 1
    if (t < NDIM) sb[t] = blin[NDIM + t];
    if (t < 2 * BB) {
        int dd = t >> 4, bq = t & 15;
        int q = s_src[(1 - dd) * BB + bq];
        int c = 0;
        for (int bb = 0; bb < BB; bb++)
            if (s_src[(1 - dd) * BB + bb] == q) { c = bb; break; }
        s_canon[dd][bq] = c;
    }
    {
        int bq = t >> 5, kk = t & 31;
        sx[bq * 128 + kk] = ent_emb[(size_t)s_src[bq] * NDIM + kk];           // hemb
        sx[bq * 128 + 32 + kk] = ent_emb[(size_t)s_src[BB + bq] * NDIM + kk]; // temb
    }
    __syncthreads();
    for (int dd = 0; dd < 2; dd++) { // layer-2 linear on (canon,b) segments
        int bq = t >> 5, j = t & 31;
        const float* hrow = qaccB + (size_t)dd * BB * ROW + s_canon[dd][bq] * ROW + bq * NDIM;
        float s = sb[j];
        for (int kk = 0; kk < NDIM; kk++)
            s += hrow[kk] * sW[kk * NDIM + j];
        // d=0 (init=head, query=tail) -> tail_hid (col 96); d=1 -> head_hid (col 64)
        sx[bq * 128 + (dd == 0 ? 96 : 64) + j] = fmaxf(s, 0.f);
    }
    __syncthreads();
    for (int o = t; o < BB * EVAL_RELC; o += 512) {
        int bq = o / EVAL_RELC, r = o % EVAL_RELC;
        float s = br[r];
        for (int kk = 0; kk < 128; kk++)
            s += sx[bq * 128 + kk] * Wr[kk * EVAL_RELC + r];
        out[o] = s;
    }
}

extern "C" void kernel_launch(void* const* d_in, const int* in_sizes, int n_in,
                              void* d_out, int out_size, void* d_ws,
                              size_t ws_size, hipStream_t stream)
{
    const int* head = (const int*)d_in[0];
    const int* tail = (const int*)d_in[1];
    const int* eh = (const int*)d_in[2];
    const int* et = (const int*)d_in[3];
    const int* er = (const int*)d_in[4];
    const float* ew = (const float*)d_in[5];
    const float* ent_emb = (const float*)d_in[6];
    const float* rel_embs = (const float*)d_in[7];
    const float* Wlin = (const float*)d_in[8];
    const float* blin = (const float*)d_in[9];
    const float* Wrel = (const float*)d_in[10];
    const float* brel = (const float*)d_in[11];
    const float* Watt = (const float*)d_in[12];
    const float* batt = (const float*)d_in[13];
    const float* Wr = (const float*)d_in[14];
    const float* br = (const float*)d_in[15];
    float* out = (float*)d_out;
    float* ws = (float*)d_ws;

    // ---- workspace carve (~7.8 MB; relwG eliminated) ----
    int4* recs = (int4*)ws;                           // [4][NE] int4
    int* counts = (int*)(recs + (size_t)4 * NE);      // [NSCAN][4]
    float* qaccB = (float*)(counts + 4 * NSCAN);      // [2][16][512]
    int* done = (int*)(qaccB + (size_t)2 * BB * ROW); // 1 int

    k_scan<<<NSCAN, 512, 0, stream>>>(head, tail, eh, et, er, ew,
                                      recs, counts, qaccB, done);
    k_gather<<<NSCAN, 512, 0, stream>>>(head, tail, ent_emb, rel_embs,
                                        Wlin, blin, Wrel, brel, Watt, batt,
                                        Wr, br, recs, counts, qaccB, done, out);
}